// Round 12
// baseline (213.477 us; speedup 1.0000x reference)
//
#include <hip/hip_runtime.h>

typedef unsigned int uint;
typedef __attribute__((ext_vector_type(4))) float f4;

#define SCALEF 0.08838834764831845f   // 128^-0.5
#define NBINS 4096
#define CAND_MAX 4096
#define SELC 1024
#define LLIST 512
#define T_LOOSE 4.0f      // static collect threshold (~600 cands/batch; s64 ~ 4.6)

__device__ __forceinline__ uint ordmap(float v) {
  uint u = __float_as_uint(v);
  return (u & 0x80000000u) ? ~u : (u | 0x80000000u);   // order-preserving map
}

#define DOT4(a, b2) ((a).x*(b2).x + (a).y*(b2).y + (a).z*(b2).z + (a).w*(b2).w)

// ---------------- K_prep: factored score basis (conflict-free, wide-parallel) ----
// s(l,m) = g_l . x_m + h_l (exact fp32, SCALEF folded in)
// A = Wq Wk^T (16x16), u_d = Wq[d,:].bk, v_e = bq.Wk[e,:], c = bq.bk
__global__ __launch_bounds__(256) void k_prep(const float* __restrict__ x,
    const float* __restrict__ Wq, const float* __restrict__ bq,
    const float* __restrict__ Wk, const float* __restrict__ bk,
    float* __restrict__ Gv, float* __restrict__ Hv, uint* __restrict__ ccnt) {
  __shared__ float sWq[2048];
  __shared__ float sWkT[128 * 17];     // transposed [h][e], pad 17 kills bank conflicts
  __shared__ float sA[256];
  __shared__ float su[16], sv[16], sc_sh;
  __shared__ float sbq[128], sbk[128];
  int tid = threadIdx.x;
  int row = blockIdx.x * 256 + tid;     // 0..65535 (b*1024+l)
  if (blockIdx.x == 0 && tid < 64) ccnt[tid] = 0;
  for (int i = tid; i < 512; i += 256) {
    ((float4*)sWq)[i] = ((const float4*)Wq)[i];
    float4 k4 = ((const float4*)Wk)[i];
    int d = i >> 5, h4 = (i & 31) * 4;
    sWkT[(h4 + 0) * 17 + d] = k4.x;
    sWkT[(h4 + 1) * 17 + d] = k4.y;
    sWkT[(h4 + 2) * 17 + d] = k4.z;
    sWkT[(h4 + 3) * 17 + d] = k4.w;
  }
  if (tid < 128) { sbq[tid] = bq[tid]; sbk[tid] = bk[tid]; }
  __syncthreads();
  {  // A[d][e], conflict-free both operands
    int d = tid >> 4, e = tid & 15;
    float s = 0.f;
#pragma unroll 8
    for (int h = 0; h < 128; h++) s += sWq[d * 128 + h] * sWkT[h * 17 + e];
    sA[tid] = s * SCALEF;
  }
  if (tid < 128) {                      // su[d] via 8-thread partial + shuffle reduce
    int d = tid >> 3, part = tid & 7;
    float s = 0.f;
#pragma unroll
    for (int h2 = 0; h2 < 16; h2++) s += sWq[d * 128 + part * 16 + h2] * sbk[part * 16 + h2];
#pragma unroll
    for (int off = 1; off < 8; off <<= 1) s += __shfl_xor(s, off);
    if (part == 0) su[d] = s * SCALEF;
  } else {                              // sv[e] likewise
    int e = (tid - 128) >> 3, part = tid & 7;
    float s = 0.f;
#pragma unroll
    for (int h2 = 0; h2 < 16; h2++) s += sbq[part * 16 + h2] * sWkT[(part * 16 + h2) * 17 + e];
#pragma unroll
    for (int off = 1; off < 8; off <<= 1) s += __shfl_xor(s, off);
    if (part == 0) sv[e] = s * SCALEF;
  }
  __syncthreads();
  if (tid < 64) {                       // sc via 64-lane reduce
    float s = sbq[tid] * sbk[tid] + sbq[tid + 64] * sbk[tid + 64];
#pragma unroll
    for (int off = 1; off < 64; off <<= 1) s += __shfl_xor(s, off);
    if (tid == 0) sc_sh = s * SCALEF;
  }
  __syncthreads();
  float xr[16];
#pragma unroll
  for (int d = 0; d < 16; d += 4) *(float4*)&xr[d] = *(const float4*)&x[(size_t)row * 16 + d];
  float g[16];
#pragma unroll
  for (int e = 0; e < 16; e++) {
    float s = sv[e];
#pragma unroll
    for (int d = 0; d < 16; d++) s += xr[d] * sA[d * 16 + e];
    g[e] = s;
  }
  float hh = sc_sh;
#pragma unroll
  for (int d = 0; d < 16; d++) hh += xr[d] * su[d];
#pragma unroll
  for (int e = 0; e < 16; e += 4) *(float4*)&Gv[(size_t)row * 16 + e] = *(float4*)&g[e];
  Hv[row] = hh;
}

// ---------------- K1: hot collect, memory-op-free inner loop + hit masks ----------
// 2048 blocks, XCD-bijective: xcdgrp = i&7 owns 8 whole batches (L2-resident ~1MB).
// Tile 256x128: lane owns rows {lane+64k}; wave w owns cols [32w,32w+32).
// Inner loop: 64 FMA + 4 mask-ORs per cc; NO stores/atomics => g stays in VGPRs.
// Hits (rare, ~11/block) recomputed and pushed after the loop.
__global__ __launch_bounds__(256, 4) void k_score(const float* __restrict__ Gv,
    const float* __restrict__ Hv, const float* __restrict__ x,
    uint* __restrict__ ccnt, int* __restrict__ cidx, float* __restrict__ cval) {
  int i = blockIdx.x;
  int g8 = i & 7, j = i >> 3;
  int b = g8 * 8 + (j & 7);             // XCD-group g8 -> batches [8*g8, 8*g8+8)
  int t = j >> 3;                       // 0..31
  int tm = t >> 3, tn = t & 7;
  __shared__ f4 sX4[512];               // 128 cols x 16 d (8 KB)
  __shared__ int lidx[LLIST];
  __shared__ float lval[LLIST];
  __shared__ uint lcnt, base_sh;
  int tid = threadIdx.x;
  if (tid == 0) lcnt = 0;
  const f4* xsrc = (const f4*)(x + ((size_t)b * 1024 + tn * 128) * 16);
  sX4[tid] = xsrc[tid];
  sX4[tid + 256] = xsrc[tid + 256];
  int lane = tid & 63, w = tid >> 6;
  const f4* gp = (const f4*)(Gv + ((size_t)b * 1024 + tm * 256 + lane) * 16);
  f4 gr0[4], gr1[4], gr2[4], gr3[4];
#pragma unroll
  for (int q = 0; q < 4; q++) {
    gr0[q] = gp[q]; gr1[q] = gp[256 + q]; gr2[q] = gp[512 + q]; gr3[q] = gp[768 + q];
  }
  float hv0 = Hv[b * 1024 + tm * 256 + lane];
  float hv1 = Hv[b * 1024 + tm * 256 + lane + 64];
  float hv2 = Hv[b * 1024 + tm * 256 + lane + 128];
  float hv3 = Hv[b * 1024 + tm * 256 + lane + 192];
  int r0g = tm * 256 + lane, c0g = tn * 128;
  uint m0 = 0, m1 = 0, m2 = 0, m3 = 0;
  __syncthreads();

#pragma unroll 4
  for (int cc = 0; cc < 32; ++cc) {
    int c = w * 32 + cc;                 // wave-uniform column
    f4 x0 = sX4[c * 4 + 0], x1 = sX4[c * 4 + 1];
    f4 x2 = sX4[c * 4 + 2], x3 = sX4[c * 4 + 3];
    float s0 = (hv0 + DOT4(gr0[0], x0) + DOT4(gr0[1], x1)) + (DOT4(gr0[2], x2) + DOT4(gr0[3], x3));
    float s1 = (hv1 + DOT4(gr1[0], x0) + DOT4(gr1[1], x1)) + (DOT4(gr1[2], x2) + DOT4(gr1[3], x3));
    float s2 = (hv2 + DOT4(gr2[0], x0) + DOT4(gr2[1], x1)) + (DOT4(gr2[2], x2) + DOT4(gr2[3], x3));
    float s3 = (hv3 + DOT4(gr3[0], x0) + DOT4(gr3[1], x1)) + (DOT4(gr3[2], x2) + DOT4(gr3[3], x3));
    m0 |= (s0 >= T_LOOSE ? 1u : 0u) << cc;
    m1 |= (s1 >= T_LOOSE ? 1u : 0u) << cc;
    m2 |= (s2 >= T_LOOSE ? 1u : 0u) << cc;
    m3 |= (s3 >= T_LOOSE ? 1u : 0u) << cc;
  }

  // post-loop collection: recompute hits from resident gr + sX4, push to LDS list
#define COLLECT(MK, GRA, HVA, KOFF)                                              \
  while (MK) {                                                                   \
    int c2 = __ffs(MK) - 1; MK &= MK - 1;                                        \
    int c = w * 32 + c2;                                                         \
    f4 x0 = sX4[c * 4 + 0], x1 = sX4[c * 4 + 1];                                 \
    f4 x2 = sX4[c * 4 + 2], x3 = sX4[c * 4 + 3];                                 \
    float s = (HVA + DOT4(GRA[0], x0) + DOT4(GRA[1], x1))                        \
            + (DOT4(GRA[2], x2) + DOT4(GRA[3], x3));                             \
    uint pos = atomicAdd(&lcnt, 1u);                                             \
    int fi = (r0g + KOFF) * 1024 + (c0g + c);                                    \
    if (pos < LLIST) { lidx[pos] = fi; lval[pos] = s; }                          \
    else { uint gq = atomicAdd(&ccnt[b], 1u);                                    \
           if (gq < CAND_MAX) { cidx[b * CAND_MAX + gq] = fi;                    \
                                cval[b * CAND_MAX + gq] = s; } }                 \
  }
  COLLECT(m0, gr0, hv0, 0)
  COLLECT(m1, gr1, hv1, 64)
  COLLECT(m2, gr2, hv2, 128)
  COLLECT(m3, gr3, hv3, 192)
#undef COLLECT

  __syncthreads();
  uint n = lcnt > LLIST ? LLIST : lcnt;
  if (tid == 0) base_sh = atomicAdd(&ccnt[b], n);    // ONE global atomic per block
  __syncthreads();
  for (uint j2 = tid; j2 < n; j2 += 256) {
    uint p = base_sh + j2;
    if (p < CAND_MAX) { cidx[b * CAND_MAX + p] = lidx[j2]; cval[b * CAND_MAX + p] = lval[j2]; }
  }
}

// ---- 1024-thread suffix scan + boundary-bin search over 4096-bin LDS hist ----
__device__ __forceinline__ void suffix_find(const uint* __restrict__ h1,
    uint* __restrict__ wtot, int tid, uint K,
    uint* __restrict__ bin_out, uint* __restrict__ above_out) {
  int lane = tid & 63, w = tid >> 6;               // 16 waves
  uint s = h1[tid * 4] + h1[tid * 4 + 1] + h1[tid * 4 + 2] + h1[tid * 4 + 3];
  uint acc = s;
#pragma unroll
  for (int off = 1; off < 64; off <<= 1) {
    uint o = __shfl_down(acc, off);
    if (lane + off < 64) acc += o;
  }
  if (lane == 0) wtot[w] = acc;
  __syncthreads();
  uint wsuf = 0;
#pragma unroll
  for (int ww = 0; ww < 16; ww++) if (ww > w) wsuf += wtot[ww];
  uint suf_incl = acc + wsuf;
  uint suf_excl = suf_incl - s;
  if (suf_excl < K && suf_incl >= K) {             // exactly one tid
    uint run = suf_excl;
    for (int i2 = 3; i2 >= 0; i2--) {
      uint hv = h1[tid * 4 + i2];
      run += hv;
      if (run >= K) { *bin_out = (uint)(tid * 4 + i2); *above_out = run - hv; break; }
    }
  }
  __syncthreads();
}

// ---------------- K4 (1024 thr): [fallback] + direct/radix top-64 + fused MLPs ----
__global__ __launch_bounds__(1024) void k_final(const float* __restrict__ x,
    const float* __restrict__ Gv, const float* __restrict__ Hv,
    const float* __restrict__ phiW1, const float* __restrict__ phib1,
    const float* __restrict__ phiW2, const float* __restrict__ phib2,
    const float* __restrict__ xiW1, const float* __restrict__ xib1,
    const float* __restrict__ xiW2, const float* __restrict__ xib2,
    const float* __restrict__ rhoW1, const float* __restrict__ rhob1,
    const float* __restrict__ rhoW2, const float* __restrict__ rhob2,
    const uint* __restrict__ ccnt, const int* __restrict__ cidx, const float* __restrict__ cval,
    float* __restrict__ out) {
  int b = blockIdx.x;
  int tid = threadIdx.x;                // 0..1023
  __shared__ float svals[CAND_MAX];
  __shared__ int   sidxs[CAND_MAX];
  __shared__ uint  h1[NBINS];
  __shared__ uint  wtot[16];
  __shared__ uint  bin_sh, above_sh;
  __shared__ float cv[SELC];
  __shared__ int   ci[SELC];
  __shared__ int   scnt_sh, fcnt_sh;
  __shared__ float sel_v[64], sel_w[64];
  __shared__ int   sel_l[64], sel_m[64];
  __shared__ float xpair[2048];
  __shared__ float psv[8][128], ppv[8][128];
  __shared__ float hsv[128], hpv[128];
  __shared__ float pacc[8][128];
  __shared__ float vec1[128], vec2[128];
  __shared__ float wsums[2];

  uint cmain = ccnt[b];
  int fl = (cmain < 64 || cmain > CAND_MAX) ? 1 : 0;
  int cnt;
  if (tid == 0) { scnt_sh = 0; fcnt_sh = 0; }
  if (tid < 64) { sel_v[tid] = -1e30f; sel_l[tid] = 0; sel_m[tid] = 0; }

  if (!fl) {
    cnt = (int)cmain;
    for (int j = tid; j < cnt; j += 1024) {
      svals[j] = cval[(size_t)b * CAND_MAX + j];
      sidxs[j] = cidx[(size_t)b * CAND_MAX + j];
    }
    __syncthreads();
  } else {
    // ---- exact in-block fallback: 2-level radix over all 1M recomputed scores ----
    float xm[16];
#pragma unroll
    for (int d = 0; d < 16; d += 4) *(float4*)&xm[d] = *(const float4*)&x[((size_t)b * 1024 + tid) * 16 + d];
    for (int s2 = tid; s2 < NBINS; s2 += 1024) h1[s2] = 0;
    __syncthreads();
    for (int l = 0; l < 1024; l++) {
      float s = Hv[b * 1024 + l];
      const float* gl = Gv + ((size_t)b * 1024 + l) * 16;
#pragma unroll
      for (int d = 0; d < 16; d++) s += gl[d] * xm[d];
      atomicAdd(&h1[ordmap(s) >> 20], 1u);
    }
    __syncthreads();
    suffix_find(h1, wtot, tid, 64u, &bin_sh, &above_sh);
    uint B1f = bin_sh;
    uint needf = 64u - above_sh;
    for (int s2 = tid; s2 < NBINS; s2 += 1024) h1[s2] = 0;
    __syncthreads();
    for (int l = 0; l < 1024; l++) {
      float s = Hv[b * 1024 + l];
      const float* gl = Gv + ((size_t)b * 1024 + l) * 16;
#pragma unroll
      for (int d = 0; d < 16; d++) s += gl[d] * xm[d];
      uint um = ordmap(s);
      if ((um >> 20) == B1f) atomicAdd(&h1[(um >> 8) & 0xfffu], 1u);
    }
    __syncthreads();
    suffix_find(h1, wtot, tid, needf, &bin_sh, &above_sh);
    uint Pf = (B1f << 12) | bin_sh;
    for (int l = 0; l < 1024; l++) {
      float s = Hv[b * 1024 + l];
      const float* gl = Gv + ((size_t)b * 1024 + l) * 16;
#pragma unroll
      for (int d = 0; d < 16; d++) s += gl[d] * xm[d];
      uint um = ordmap(s);
      if ((um >> 8) >= Pf) {
        int pos = atomicAdd(&fcnt_sh, 1);
        if (pos < CAND_MAX) { svals[pos] = s; sidxs[pos] = l * 1024 + tid; }
      }
    }
    __syncthreads();
    cnt = fcnt_sh < CAND_MAX ? fcnt_sh : CAND_MAX;
  }

  if (cnt <= 2048) {
    // ---- direct one-shot rank selection over the staged list (no radix) ----
    for (int j = tid; j < cnt; j += 1024) {
      float vj = svals[j]; int ij = sidxs[j];
      int rank = 0;
      for (int i2 = 0; i2 < cnt; i2++) {
        float vi = svals[i2]; int ii = sidxs[i2];
        rank += (vi > vj || (vi == vj && ii < ij)) ? 1 : 0;
      }
      if (rank < 64) { sel_v[rank] = vj; sel_l[rank] = ij >> 10; sel_m[rank] = ij & 1023; }
    }
    __syncthreads();
  } else {
    // ---- radix narrow then rank (rare path) ----
    for (int s = tid; s < NBINS; s += 1024) h1[s] = 0;
    __syncthreads();
    for (int j = tid; j < cnt; j += 1024) atomicAdd(&h1[ordmap(svals[j]) >> 20], 1u);
    __syncthreads();
    suffix_find(h1, wtot, tid, 64u, &bin_sh, &above_sh);
    uint B1 = bin_sh;
    uint need = 64u - above_sh;
    for (int s = tid; s < NBINS; s += 1024) h1[s] = 0;
    __syncthreads();
    for (int j = tid; j < cnt; j += 1024) {
      uint um = ordmap(svals[j]);
      if ((um >> 20) == B1) atomicAdd(&h1[(um >> 8) & 0xfffu], 1u);
    }
    __syncthreads();
    suffix_find(h1, wtot, tid, need, &bin_sh, &above_sh);
    uint P = (B1 << 12) | bin_sh;
    for (int j = tid; j < cnt; j += 1024) {
      uint um = ordmap(svals[j]);
      if ((um >> 8) >= P) {
        int pos = atomicAdd(&scnt_sh, 1);
        if (pos < SELC) { cv[pos] = svals[j]; ci[pos] = sidxs[j]; }
      }
    }
    __syncthreads();
    int S = scnt_sh < SELC ? scnt_sh : SELC;
    for (int j = tid; j < S; j += 1024) {
      float vj = cv[j]; int ij = ci[j];
      int rank = 0;
      for (int i2 = 0; i2 < S; i2++) {
        float vi = cv[i2]; int ii = ci[i2];
        rank += (vi > vj || (vi == vj && ii < ij)) ? 1 : 0;
      }
      if (rank < 64) { sel_v[rank] = vj; sel_l[rank] = ij >> 10; sel_m[rank] = ij & 1023; }
    }
    __syncthreads();
  }

  // softmax + wsums (wave 0) || xpair float4 staging (tid>=512)
  if (tid < 64) {
    float e = expf(sel_v[tid] - sel_v[0]);
    float ssum = e;
#pragma unroll
    for (int off = 1; off < 64; off <<= 1) ssum += __shfl_xor(ssum, off);
    float wj = e / ssum;
    sel_w[tid] = wj;
    int isself = (sel_l[tid] == sel_m[tid]) ? 1 : 0;
    float s0 = isself ? wj : 0.f, s1 = isself ? 0.f : wj;
#pragma unroll
    for (int off = 1; off < 64; off <<= 1) { s0 += __shfl_xor(s0, off); s1 += __shfl_xor(s1, off); }
    if (tid == 0) { wsums[0] = s0; wsums[1] = s1; }
  } else if (tid >= 512) {
    int t2 = tid - 512;                  // 0..511 = 64 pairs x 8 float4
    int j = t2 >> 3, q = t2 & 7;
    int r = (q < 4) ? sel_l[j] : sel_m[j];
    ((float4*)xpair)[j * 8 + q] = *(const float4*)&x[((size_t)b * 1024 + r) * 16 + (q & 3) * 4];
  }
  __syncthreads();

  // feature phase: 8 j-slices x 128 h; W1 columns in registers per thread
  {
    int slice = tid >> 7, h = tid & 127;
    float wphi[16], wxi[32];
#pragma unroll
    for (int d = 0; d < 16; d++) wphi[d] = phiW1[d * 128 + h];
#pragma unroll
    for (int d = 0; d < 32; d++) wxi[d] = xiW1[d * 128 + h];
    float bphi = phib1[h], bxi = xib1[h];
    float accphi = 0.f, accxi = 0.f;
#pragma unroll
    for (int jj = 0; jj < 8; jj++) {
      int j = slice * 8 + jj;
      int l = sel_l[j], m = sel_m[j];
      float wj = sel_w[j];
      if (l == m) {
        float a = bphi;
#pragma unroll
        for (int d = 0; d < 16; d++) a += xpair[j * 32 + d] * wphi[d];
        accphi += wj * fmaxf(a, 0.f);
      } else {
        float a = bxi;
#pragma unroll
        for (int d = 0; d < 32; d++) a += xpair[j * 32 + d] * wxi[d];
        accxi += wj * fmaxf(a, 0.f);
      }
    }
    psv[slice][h] = accphi;
    ppv[slice][h] = accxi;
  }
  __syncthreads();
  if (tid < 256) {
    int hh = tid & 127;
    float s = 0.f;
    if (tid < 128) {
#pragma unroll
      for (int s2 = 0; s2 < 8; s2++) s += psv[s2][hh];
      hsv[hh] = s;
    } else {
#pragma unroll
      for (int s2 = 0; s2 < 8; s2++) s += ppv[s2][hh];
      hpv[hh] = s;
    }
  }
  __syncthreads();

  // GEMV1: vec1 = wsums.b2 + hsv@phiW2 + hpv@xiW2
  {
    int sl = tid >> 7, o = tid & 127;
    float p = 0.f;
#pragma unroll
    for (int hh2 = 0; hh2 < 16; hh2++) {
      int hh = sl * 16 + hh2;
      p += hsv[hh] * phiW2[hh * 128 + o] + hpv[hh] * xiW2[hh * 128 + o];
    }
    pacc[sl][o] = p;
  }
  __syncthreads();
  if (tid < 128) {
    float p = wsums[0] * phib2[tid] + wsums[1] * xib2[tid];
#pragma unroll
    for (int s2 = 0; s2 < 8; s2++) p += pacc[s2][tid];
    vec1[tid] = p;
  }
  __syncthreads();
  // GEMV2: vec2 = relu(vec1@rhoW1 + rhob1)
  {
    int sl = tid >> 7, o = tid & 127;
    float p = 0.f;
#pragma unroll
    for (int hh2 = 0; hh2 < 16; hh2++) {
      int hh = sl * 16 + hh2;
      p += vec1[hh] * rhoW1[hh * 128 + o];
    }
    pacc[sl][o] = p;
  }
  __syncthreads();
  if (tid < 128) {
    float r = rhob1[tid];
#pragma unroll
    for (int s2 = 0; s2 < 8; s2++) r += pacc[s2][tid];
    vec2[tid] = fmaxf(r, 0.f);
  }
  __syncthreads();
  // GEMV3: out = vec2@rhoW2 + rhob2
  {
    int sl = tid >> 7, o = tid & 127;
    float p = 0.f;
#pragma unroll
    for (int hh2 = 0; hh2 < 16; hh2++) {
      int hh = sl * 16 + hh2;
      p += vec2[hh] * rhoW2[hh * 128 + o];
    }
    pacc[sl][o] = p;
  }
  __syncthreads();
  if (tid < 128) {
    float o2 = rhob2[tid];
#pragma unroll
    for (int s2 = 0; s2 < 8; s2++) o2 += pacc[s2][tid];
    out[(size_t)b * 128 + tid] = o2;
  }
}

// ---------------- launch ----------------
extern "C" void kernel_launch(void* const* d_in, const int* in_sizes, int n_in,
                              void* d_out, int out_size, void* d_ws, size_t ws_size,
                              hipStream_t stream) {
  (void)in_sizes; (void)n_in; (void)out_size; (void)ws_size;
  const float* x     = (const float*)d_in[0];
  const float* Wq    = (const float*)d_in[1];
  const float* bq    = (const float*)d_in[2];
  const float* Wk    = (const float*)d_in[3];
  const float* bk    = (const float*)d_in[4];
  const float* phiW1 = (const float*)d_in[5];
  const float* phib1 = (const float*)d_in[6];
  const float* phiW2 = (const float*)d_in[7];
  const float* phib2 = (const float*)d_in[8];
  const float* xiW1  = (const float*)d_in[9];
  const float* xib1  = (const float*)d_in[10];
  const float* xiW2  = (const float*)d_in[11];
  const float* xib2  = (const float*)d_in[12];
  const float* rhoW1 = (const float*)d_in[13];
  const float* rhob1 = (const float*)d_in[14];
  const float* rhoW2 = (const float*)d_in[15];
  const float* rhob2 = (const float*)d_in[16];

  // workspace layout (~6.3 MB)
  char* ws = (char*)d_ws;
  float* Gv   = (float*)(ws);                      // 4 MB
  float* Hv   = (float*)(ws + 4194304);            // 256 KB
  uint*  ccnt = (uint*)(ws + 4456448);             // 256 B (+pad)
  int*   cidx = (int*)(ws + 4457472);              // 1 MB
  float* cval = (float*)(ws + 5506048);            // 1 MB

  k_prep<<<256, 256, 0, stream>>>(x, Wq, bq, Wk, bk, Gv, Hv, ccnt);
  k_score<<<2048, 256, 0, stream>>>(Gv, Hv, x, ccnt, cidx, cval);
  k_final<<<64, 1024, 0, stream>>>(x, Gv, Hv,
                                  phiW1, phib1, phiW2, phib2,
                                  xiW1, xib1, xiW2, xib2,
                                  rhoW1, rhob1, rhoW2, rhob2,
                                  ccnt, cidx, cval,
                                  (float*)d_out);
}